// Round 6
// baseline (103.892 us; speedup 1.0000x reference)
//
#include <hip/hip_runtime.h>

// out = F_amp(MLP(z_i, z_j, sep_xy2)) * (dxy / sep_r2)
// Weights W2/W3 (200 floats) preloaded ONCE per thread into VGPR f32x2 pairs
// -> v_pk_fma_f32 sources weights from VGPRs, no per-element s_load streams
// (SMEM is out-of-order => each in-loop use forced lgkmcnt(0) drains; that
// was the shared ~69us floor of R3/R4). Small tensors (W1,b*,W4 = 71 floats)
// stay on the scalar path: they fit in SGPRs persistently and hoist.
// Grid-stride batch of 4 pairs/thread amortizes the preload.

typedef float f32x4 __attribute__((ext_vector_type(4)));
typedef float f32x2 __attribute__((ext_vector_type(2)));

#define PP 4   // pairs per thread

__device__ __forceinline__ f32x2 fma2(f32x2 a, f32x2 b, f32x2 c) {
    return __builtin_elementwise_fma(a, b, c);
}

__device__ __forceinline__ f32x2 lrelu2(f32x2 x) {
    return __builtin_elementwise_max(x, x * 0.1f);   // alpha=0.1
}

__device__ __forceinline__ float tanh_fast(float x) {
    // tanh(x) = 1 - 2/(exp(2x)+1); v_exp + v_rcp, exact limits at +-inf
    float e = __expf(2.0f * x);
    return 1.0f - 2.0f * __builtin_amdgcn_rcpf(e + 1.0f);
}

__device__ __forceinline__ f32x2 uld2(const float* __restrict__ p) {
    return *reinterpret_cast<const f32x2*>(p);
}

__global__ void __launch_bounds__(256, 2) fused_mlp_kernel(
    const float* __restrict__ in,
    const float* __restrict__ W1, const float* __restrict__ b1,
    const float* __restrict__ W2, const float* __restrict__ b2,
    const float* __restrict__ W3, const float* __restrict__ b3,
    const float* __restrict__ W4, const float* __restrict__ b4,
    float* __restrict__ out, int npairs)
{
    // ---- one-time: W2, W3 into per-lane VGPR pairs (pk_fma operands) ----
    f32x2 w2p[50], w3p[50];
    #pragma unroll
    for (int k = 0; k < 50; ++k) w2p[k] = uld2(W2 + 2 * k);
    #pragma unroll
    for (int k = 0; k < 50; ++k) w3p[k] = uld2(W3 + 2 * k);

    const f32x4* in4 = reinterpret_cast<const f32x4*>(in);
    f32x4* out4 = reinterpret_cast<f32x4*>(out);

    int tid = blockIdx.x * blockDim.x + threadIdx.x;
    int stride = gridDim.x * blockDim.x;

    #pragma unroll
    for (int it = 0; it < PP; ++it) {
        int p = tid + it * stride;
        if (p >= npairs) continue;

        f32x4 A = in4[3 * p + 0];
        f32x4 B = in4[3 * p + 1];
        f32x4 C = in4[3 * p + 2];

        // element0 = {A0 A1 A2 A3 B0 B1}, element1 = {B2 B3 C0 C1 C2 C3}
        // feature stage packed across elements (no weights, no splats)
        f32x2 px0 = {A[0], B[2]}, py0 = {A[1], B[3]}, pz0 = {A[2], C[0]};
        f32x2 px1 = {A[3], C[1]}, py1 = {B[0], C[2]}, pz1 = {B[1], C[3]};

        f32x2 dx = px1 - px0;
        f32x2 dy = py1 - py0;
        f32x2 dz = pz1 - pz0;
        f32x2 sep_xy2 = fma2(dx, dx, dy * dy);
        f32x2 sep_r2  = fma2(dz, dz, sep_xy2);
        f32x2 inv_r2  = {__builtin_amdgcn_rcpf(sep_r2[0]),
                         __builtin_amdgcn_rcpf(sep_r2[1])};

        float oo[4];

        #pragma unroll
        for (int e = 0; e < 2; ++e) {
            // MLP packed across NEURON pairs (j, j+1); weights = natural pairs
            float zin[3] = {pz0[e], pz1[e], sep_xy2[e]};

            // Layer 1: [3] -> [10], leaky relu (small: scalar path weights)
            f32x2 acc1[5];
            #pragma unroll
            for (int jp = 0; jp < 5; ++jp) acc1[jp] = uld2(b1 + 2 * jp);
            #pragma unroll
            for (int i = 0; i < 3; ++i) {
                f32x2 hs = {zin[i], zin[i]};
                #pragma unroll
                for (int jp = 0; jp < 5; ++jp)
                    acc1[jp] = fma2(hs, uld2(W1 + i * 10 + 2 * jp), acc1[jp]);
            }
            f32x2 h1[5];
            #pragma unroll
            for (int jp = 0; jp < 5; ++jp) h1[jp] = lrelu2(acc1[jp]);

            // Layer 2: [10] -> [10], tanh  (weights from VGPR pairs)
            f32x2 acc2[5];
            #pragma unroll
            for (int jp = 0; jp < 5; ++jp) acc2[jp] = uld2(b2 + 2 * jp);
            #pragma unroll
            for (int i = 0; i < 10; ++i) {
                float hv = h1[i >> 1][i & 1];
                f32x2 hs = {hv, hv};
                #pragma unroll
                for (int jp = 0; jp < 5; ++jp)
                    acc2[jp] = fma2(hs, w2p[i * 5 + jp], acc2[jp]);
            }
            f32x2 h2[5];
            #pragma unroll
            for (int jp = 0; jp < 5; ++jp) {
                f32x2 t;
                t[0] = tanh_fast(acc2[jp][0]);
                t[1] = tanh_fast(acc2[jp][1]);
                h2[jp] = t;
            }

            // Layer 3: [10] -> [10], leaky relu (weights from VGPR pairs)
            f32x2 acc3[5];
            #pragma unroll
            for (int jp = 0; jp < 5; ++jp) acc3[jp] = uld2(b3 + 2 * jp);
            #pragma unroll
            for (int i = 0; i < 10; ++i) {
                float hv = h2[i >> 1][i & 1];
                f32x2 hs = {hv, hv};
                #pragma unroll
                for (int jp = 0; jp < 5; ++jp)
                    acc3[jp] = fma2(hs, w3p[i * 5 + jp], acc3[jp]);
            }
            f32x2 h3[5];
            #pragma unroll
            for (int jp = 0; jp < 5; ++jp) h3[jp] = lrelu2(acc3[jp]);

            // Layer 4: [10] -> [1] (small: scalar path)
            f32x2 fp = {b4[0], 0.0f};
            #pragma unroll
            for (int ip = 0; ip < 5; ++ip)
                fp = fma2(h3[ip], uld2(W4 + 2 * ip), fp);
            float f = fp[0] + fp[1];

            float s = f * inv_r2[e];
            oo[2 * e + 0] = s * dx[e];
            oo[2 * e + 1] = s * dy[e];
        }

        f32x4 o;
        o[0] = oo[0]; o[1] = oo[1]; o[2] = oo[2]; o[3] = oo[3];
        out4[p] = o;
    }
}

extern "C" void kernel_launch(void* const* d_in, const int* in_sizes, int n_in,
                              void* d_out, int out_size, void* d_ws, size_t ws_size,
                              hipStream_t stream) {
    const float* in = (const float*)d_in[0];
    const float* W1 = (const float*)d_in[1];
    const float* b1 = (const float*)d_in[2];
    const float* W2 = (const float*)d_in[3];
    const float* b2 = (const float*)d_in[4];
    const float* W3 = (const float*)d_in[5];
    const float* b3 = (const float*)d_in[6];
    const float* W4 = (const float*)d_in[7];
    const float* b4 = (const float*)d_in[8];
    float* out = (float*)d_out;

    int npairs = out_size / 4;                       // 2 elements per pair
    int nthreads = (npairs + PP - 1) / PP;           // PP pairs per thread
    int blocks = (nthreads + 255) / 256;
    fused_mlp_kernel<<<blocks, 256, 0, stream>>>(
        in, W1, b1, W2, b2, W3, b3, W4, b4, out, npairs);
}

// Round 7
// 71.855 us; speedup vs baseline: 1.4459x; 1.4459x over previous
//
#include <hip/hip_runtime.h>

// out = F_amp(MLP(z_i, z_j, sep_xy2)) * (dxy / sep_r2)
// Neuron-pair packing (f32x2 = neurons 2j,2j+1). Weights = contiguous SGPR
// pairs ("s" asm constraint). Activation broadcast is FREE via VOP3P op_sel
// (v_pk_fma_f32 op_sel splats either half of src0) -- no splat movs, no
// pair-half extract movs. Bias rides the first FMA's c operand (VGPR).
// tanh: exp2 with folded literal 2*log2(e), add/rcp/fma with inline consts.

typedef float f32x4 __attribute__((ext_vector_type(4)));
typedef float f32x2 __attribute__((ext_vector_type(2)));

// d = splat(a[half]) * w + c   (w pinned to SGPR pair; 1 SGPR source is legal)
__device__ __forceinline__ f32x2 fma2_splat(f32x2 a, int half, f32x2 w, f32x2 c) {
    f32x2 d;
    if (half == 0) {
        asm("v_pk_fma_f32 %0, %1, %2, %3 op_sel:[0,0,0] op_sel_hi:[0,1,1]"
            : "=v"(d) : "v"(a), "s"(w), "v"(c));
    } else {
        asm("v_pk_fma_f32 %0, %1, %2, %3 op_sel:[1,0,0] op_sel_hi:[1,1,1]"
            : "=v"(d) : "v"(a), "s"(w), "v"(c));
    }
    return d;
}

__device__ __forceinline__ f32x2 fma2(f32x2 a, f32x2 b, f32x2 c) {
    return __builtin_elementwise_fma(a, b, c);
}

__device__ __forceinline__ f32x2 lrelu2(f32x2 x) {
    return __builtin_elementwise_max(x, x * 0.1f);   // alpha=0.1
}

__device__ __forceinline__ float tanh_fast(float x) {
    // tanh(x) = 1 - 2/(exp2(x*2log2e)+1): mul(lit)+exp+add(1.0)+rcp+fma(-2,1)
    float e = __builtin_amdgcn_exp2f(x * 2.8853900817779268f);
    return fmaf(-2.0f, __builtin_amdgcn_rcpf(e + 1.0f), 1.0f);
}

__device__ __forceinline__ f32x2 uld2(const float* __restrict__ p) {
    return *reinterpret_cast<const f32x2*>(p);       // uniform -> SGPR pair
}

__global__ void __launch_bounds__(256) fused_mlp_kernel(
    const float* __restrict__ in,
    const float* __restrict__ W1, const float* __restrict__ b1,
    const float* __restrict__ W2, const float* __restrict__ b2,
    const float* __restrict__ W3, const float* __restrict__ b3,
    const float* __restrict__ W4, const float* __restrict__ b4,
    float* __restrict__ out, int npairs)
{
    int p = blockIdx.x * blockDim.x + threadIdx.x;
    if (p >= npairs) return;

    const f32x4* in4 = reinterpret_cast<const f32x4*>(in);
    f32x4 A = in4[3 * p + 0];
    f32x4 B = in4[3 * p + 1];
    f32x4 C = in4[3 * p + 2];

    // element0 = {A0 A1 A2 A3 B0 B1}, element1 = {B2 B3 C0 C1 C2 C3}
    float xs[2][6] = {
        {A[0], A[1], A[2], A[3], B[0], B[1]},
        {B[2], B[3], C[0], C[1], C[2], C[3]}
    };

    float oo[4];

    #pragma unroll
    for (int e = 0; e < 2; ++e) {
        float dx = xs[e][3] - xs[e][0];
        float dy = xs[e][4] - xs[e][1];
        float dz = xs[e][5] - xs[e][2];
        float sep_xy2 = fmaf(dx, dx, dy * dy);
        float sep_r2  = fmaf(dz, dz, sep_xy2);
        float inv_r2  = __builtin_amdgcn_rcpf(sep_r2);

        // z inputs packed as pairs so op_sel can splat each half for free
        f32x2 zA; zA[0] = xs[e][2]; zA[1] = xs[e][5];   // {z_i, z_j}
        f32x2 zB; zB[0] = sep_xy2;  zB[1] = sep_xy2;

        // Layer 1: [3] -> [10], leaky relu. Bias fused into i=0 FMA (c=VGPR).
        f32x2 h1p[5];
        #pragma unroll
        for (int jp = 0; jp < 5; ++jp) {
            f32x2 a = fma2_splat(zA, 0, uld2(W1 + 0 * 10 + 2 * jp), uld2(b1 + 2 * jp));
            a = fma2_splat(zA, 1, uld2(W1 + 1 * 10 + 2 * jp), a);
            a = fma2_splat(zB, 0, uld2(W1 + 2 * 10 + 2 * jp), a);
            h1p[jp] = lrelu2(a);
        }

        // Layer 2: [10] -> [10], tanh
        f32x2 h2p[5];
        #pragma unroll
        for (int jp = 0; jp < 5; ++jp) {
            f32x2 a = fma2_splat(h1p[0], 0, uld2(W2 + 0 * 10 + 2 * jp), uld2(b2 + 2 * jp));
            #pragma unroll
            for (int i = 1; i < 10; ++i)
                a = fma2_splat(h1p[i >> 1], i & 1, uld2(W2 + i * 10 + 2 * jp), a);
            f32x2 t;
            t[0] = tanh_fast(a[0]);
            t[1] = tanh_fast(a[1]);
            h2p[jp] = t;
        }

        // Layer 3: [10] -> [10], leaky relu
        f32x2 h3p[5];
        #pragma unroll
        for (int jp = 0; jp < 5; ++jp) {
            f32x2 a = fma2_splat(h2p[0], 0, uld2(W3 + 0 * 10 + 2 * jp), uld2(b3 + 2 * jp));
            #pragma unroll
            for (int i = 1; i < 10; ++i)
                a = fma2_splat(h2p[i >> 1], i & 1, uld2(W3 + i * 10 + 2 * jp), a);
            h3p[jp] = lrelu2(a);
        }

        // Layer 4: [10] -> [1]; full pk dot (no splat needed), W4 = SGPR pairs
        f32x2 fp = fma2(h3p[0], uld2(W4 + 0), (f32x2){b4[0], 0.0f});
        #pragma unroll
        for (int ip = 1; ip < 5; ++ip)
            fp = fma2(h3p[ip], uld2(W4 + 2 * ip), fp);
        float f = fp[0] + fp[1];

        float s = f * inv_r2;
        oo[2 * e + 0] = s * dx;
        oo[2 * e + 1] = s * dy;
    }

    f32x4 o;
    o[0] = oo[0]; o[1] = oo[1]; o[2] = oo[2]; o[3] = oo[3];
    reinterpret_cast<f32x4*>(out)[p] = o;
}

extern "C" void kernel_launch(void* const* d_in, const int* in_sizes, int n_in,
                              void* d_out, int out_size, void* d_ws, size_t ws_size,
                              hipStream_t stream) {
    const float* in = (const float*)d_in[0];
    const float* W1 = (const float*)d_in[1];
    const float* b1 = (const float*)d_in[2];
    const float* W2 = (const float*)d_in[3];
    const float* b2 = (const float*)d_in[4];
    const float* W3 = (const float*)d_in[5];
    const float* b3 = (const float*)d_in[6];
    const float* W4 = (const float*)d_in[7];
    const float* b4 = (const float*)d_in[8];
    float* out = (float*)d_out;

    int npairs = out_size / 4;          // 2 elements (4 output floats) per thread
    int blocks = (npairs + 255) / 256;
    fused_mlp_kernel<<<blocks, 256, 0, stream>>>(
        in, W1, b1, W2, b2, W3, b3, W4, b4, out, npairs);
}